// Round 18
// baseline (97.792 us; speedup 1.0000x reference)
//
#include <hip/hip_runtime.h>
#include <math.h>

namespace {
constexpr int NB   = 256;
constexpr int NA   = 64;
constexpr int EMBD = 64;
constexpr int HIDD = 128;
constexpr int OUTD = 512;
constexpr int FPS  = 136;  // short-stride for bf16 LDS tiles
constexpr int DSTR = 68;   // padded float-stride for s_dist
constexpr unsigned MAGIC = 0x5A5A5A5Au;   // != 0xAAAAAAAA ws-poison

typedef __attribute__((ext_vector_type(8))) short bfrag8;
typedef __attribute__((ext_vector_type(4))) float floatx4;

__device__ __forceinline__ unsigned short bf16_rne(float f) {
    unsigned u = __float_as_uint(f);
    u += 0x7fffu + ((u >> 16) & 1u);
    return (unsigned short)(u >> 16);
}

// branch-free exact-GELU: erf via Abramowitz-Stegun 7.1.26 (|err| <= 1.5e-7)
__device__ __forceinline__ float gelu_fast(float x) {
    const float ax = fabsf(x) * 0.7071067811865475f;
    const float t  = __builtin_amdgcn_rcpf(fmaf(0.3275911f, ax, 1.0f));
    float p = fmaf(1.061405429f, t, -1.453152027f);
    p = fmaf(p, t, 1.421413741f);
    p = fmaf(p, t, -0.284496736f);
    p = fmaf(p, t, 0.254829592f);
    p = p * t;
    const float e = __builtin_amdgcn_exp2f(-1.4426950408889634f * ax * ax);
    const float erfx = copysignf(fmaf(-p, e, 1.0f), x);
    const float hx   = 0.5f * x;
    return fmaf(hx, erfx, hx);
}

// ---- fused kernel: half-molecule front + last-arriver tail.
// block (mol=bid>>1, h=bid&1), 512 threads, 2 blocks/CU co-resident.
// ws layout: floats [0,65536) u-values (mol*256 + h*128 + col);
//            ints at +65536 floats: flags[mol*2+h] (winner resets to 0).
__global__ __launch_bounds__(512, 4)
void mlip_fused2(const int*   __restrict__ atomic_nums,
                 const float* __restrict__ coords,
                 const float* __restrict__ embed_table,
                 const float* __restrict__ W1, const float* __restrict__ b1,
                 const float* __restrict__ W2, const float* __restrict__ b2,
                 const float* __restrict__ Wo, const float* __restrict__ bo,
                 const float* __restrict__ centers,
                 float*       __restrict__ ws,
                 float*       __restrict__ out)
{
    const int bid  = blockIdx.x;
    const int mol  = bid >> 1, h = bid & 1;
    const int tid  = threadIdx.x;
    const int lane = tid & 63;
    const int wid  = tid >> 6;            // 8 waves

    __shared__ float s_dist[32 * DSTR];   // 8.5 KB; reused as GEMV partial buf
    __shared__ short s_w[16384];          // 32 KB: W1 frags (hi only)
    __shared__ short s_fhi[32][FPS];      // 8.5 KB feat (this half's 32 rows)
    __shared__ float s_molS[HIDD];        // atomic col-sums of gelu out
    __shared__ float s_molv[HIDD];        // winner: u0+u1+b2
    __shared__ int   s_go;

    int* flags = (int*)(ws + 65536);

    // ---- tiling ids (8 waves = 2 wm x 4 wn; wave = 16 rows x 32 cols)
    const int wn      = wid >> 1;
    const int lrow    = lane & 15, g4 = lane >> 4;
    const int arow    = ((wid & 1) << 4) + lrow;      // local row [0,32)
    const int colbase = (wn << 5) + lrow;

    // ---- GEMV ids: col x 4-way k-split
    const int gcol = tid & 127, kc = tid >> 7;        // kc in [0,4)

    // ---- gauss ids
    const int grow = tid >> 4;            // [0,32)
    const int gch  = (tid >> 2) & 3;
    const int jq   = tid & 3;

    const float b1a = b1[colbase];
    const float b1b = b1[colbase + 16];
    const float c0  = centers[gch << 4];

    if (tid < HIDD) s_molS[tid] = 0.0f;

    // ---- W1 loads phase A (slots 0..1023)
    float w1v[16];
#pragma unroll
    for (int a = 0; a < 2; ++a) {
        const int slot = (a << 9) + tid;
        const int fg = slot >> 6, ls = slot & 63;
        const int k0 = ((fg >> 3) << 5) + ((ls >> 4) << 3);
        const int n  = ((fg & 7) << 4) + (ls & 15);
        const float* src = W1 + (size_t)k0 * HIDD + n;
#pragma unroll
        for (int r = 0; r < 8; ++r) w1v[a * 8 + r] = src[(size_t)r * HIDD];
    }

    // ---- per-lane coords (atom = lane)
    const float* cbase = coords + (size_t)mol * NA * 3;
    const float cx = cbase[lane * 3 + 0];
    const float cy = cbase[lane * 3 + 1];
    const float cz = cbase[lane * 3 + 2];

    // ---- embedding for this half's 32 rows
    {
        const int i = tid >> 4, e4 = (tid & 15) << 2;
        const int z = atomic_nums[mol * NA + (h << 5) + i];
        const float4 ev = *(const float4*)(embed_table + (size_t)z * EMBD + e4);
        short4 h4;
        const float v[4] = {ev.x, ev.y, ev.z, ev.w};
        short* hp = (short*)&h4;
#pragma unroll
        for (int q = 0; q < 4; ++q) hp[q] = (short)bf16_rne(v[q]);
        *(short4*)&s_fhi[i][e4] = h4;
    }

    // ---- dists: wave w writes local rows 4w..4w+3 (within-wave dep, no barrier)
#pragma unroll
    for (int it = 0; it < 4; ++it) {
        const int i  = (wid << 2) + it;
        const int gi = (h << 5) + i;
        const float xi = __shfl(cx, gi, 64);
        const float yi = __shfl(cy, gi, 64);
        const float zi = __shfl(cz, gi, 64);
        const float dx = xi - cx, dy = yi - cy, dz = zi - cz;
        const float sq = dx * dx + dy * dy + dz * dz;
        s_dist[i * DSTR + lane] = sq > 0.0f ? sqrtf(sq) : 0.0f;
    }

    // ---- convert W1 phase A -> s_w
#pragma unroll
    for (int a = 0; a < 2; ++a) {
        unsigned Hu[4];
#pragma unroll
        for (int p = 0; p < 4; ++p) {
            const float x = w1v[a * 8 + 2 * p], y = w1v[a * 8 + 2 * p + 1];
            unsigned hh;
            asm("v_cvt_pk_bf16_f32 %0, %1, %2" : "=v"(hh) : "v"(x), "v"(y));
            Hu[p] = hh;
        }
        const int slot = (a << 9) + tid;
        const int base = ((slot >> 6) << 9) + (slot & 63) * 8;
        *(uint4*)&s_w[base] = make_uint4(Hu[0], Hu[1], Hu[2], Hu[3]);
    }

    // ---- issue W1 phase B loads; land during gauss
#pragma unroll
    for (int a = 0; a < 2; ++a) {
        const int slot = ((a + 2) << 9) + tid;
        const int fg = slot >> 6, ls = slot & 63;
        const int k0 = ((fg >> 3) << 5) + ((ls >> 4) << 3);
        const int n  = ((fg & 7) << 4) + (ls & 15);
        const float* src = W1 + (size_t)k0 * HIDD + n;
#pragma unroll
        for (int r = 0; r < 8; ++r) w1v[a * 8 + r] = src[(size_t)r * HIDD];
    }

    // ---- gaussian smear (2 ops/term, 4-way ILP chains)
    {
        constexpr float L2E   = 1.4426950408889634f;
        constexpr float DELTA = 10.0f / 63.0f;
        constexpr float K2L   = -2.0f * L2E;
        constexpr float UA    = 4.0f * DELTA * L2E;
        const float P1  = 0.95085835f,  P2  = 0.81745274f, P3  = 0.63539088f,
                    P4  = 0.44653019f,  P5  = 0.28372112f, P6  = 0.16299117f,
                    P7  = 0.08465801f,  P8  = 0.03975530f, P9  = 0.01688004f,
                    P10 = 0.00647989f,  P11 = 0.00224901f, P12 = 0.00070576f,
                    P13 = 0.00020024f,  P14 = 5.136543e-5f, P15 = 1.191313e-5f;

        float acc[16];
#pragma unroll
        for (int q = 0; q < 16; ++q) acc[q] = 0.0f;

        const float* drow = &s_dist[grow * DSTR + (jq << 4)];
#pragma unroll
        for (int j4 = 0; j4 < 4; ++j4) {
            const float4 d4 = *(const float4*)(drow + (j4 << 2));
            const float dv[4] = {d4.x, d4.y, d4.z, d4.w};
#pragma unroll
            for (int jj = 0; jj < 4; ++jj) {
                const float x  = dv[jj] - c0;
                const float A  = __builtin_amdgcn_exp2f(K2L * x * x);
                const float r  = __builtin_amdgcn_exp2f(UA * x);
                const float r2 = r * r, r4 = r2 * r2;
                float s0 = A, s1 = A * r, s2 = A * r2, s3 = s1 * r2;
                acc[0] += s0;
                acc[1]  = fmaf(s1, P1,  acc[1]);
                acc[2]  = fmaf(s2, P2,  acc[2]);
                acc[3]  = fmaf(s3, P3,  acc[3]);
                s0 *= r4; s1 *= r4; s2 *= r4; s3 *= r4;
                acc[4]  = fmaf(s0, P4,  acc[4]);
                acc[5]  = fmaf(s1, P5,  acc[5]);
                acc[6]  = fmaf(s2, P6,  acc[6]);
                acc[7]  = fmaf(s3, P7,  acc[7]);
                s0 *= r4; s1 *= r4; s2 *= r4; s3 *= r4;
                acc[8]  = fmaf(s0, P8,  acc[8]);
                acc[9]  = fmaf(s1, P9,  acc[9]);
                acc[10] = fmaf(s2, P10, acc[10]);
                acc[11] = fmaf(s3, P11, acc[11]);
                s0 *= r4; s1 *= r4; s2 *= r4; s3 *= r4;
                acc[12] = fmaf(s0, P12, acc[12]);
                acc[13] = fmaf(s1, P13, acc[13]);
                acc[14] = fmaf(s2, P14, acc[14]);
                acc[15] = fmaf(s3, P15, acc[15]);
            }
        }
#pragma unroll
        for (int q = 0; q < 16; ++q) {
            acc[q] += __shfl_xor(acc[q], 1, 64);
            acc[q] += __shfl_xor(acc[q], 2, 64);
        }
        if (jq == 0) {
            unsigned* hp = (unsigned*)&s_fhi[grow][EMBD + (gch << 4)];
#pragma unroll
            for (int q2 = 0; q2 < 8; ++q2) {
                const unsigned h0 = bf16_rne(acc[2 * q2]     * (1.0f / 64.0f));
                const unsigned h1 = bf16_rne(acc[2 * q2 + 1] * (1.0f / 64.0f));
                hp[q2] = h0 | (h1 << 16);
            }
        }
    }

    // ---- convert W1 phase B -> s_w
#pragma unroll
    for (int a = 0; a < 2; ++a) {
        unsigned Hu[4];
#pragma unroll
        for (int p = 0; p < 4; ++p) {
            const float x = w1v[a * 8 + 2 * p], y = w1v[a * 8 + 2 * p + 1];
            unsigned hh;
            asm("v_cvt_pk_bf16_f32 %0, %1, %2" : "=v"(hh) : "v"(x), "v"(y));
            Hu[p] = hh;
        }
        const int slot = ((a + 2) << 9) + tid;
        const int base = ((slot >> 6) << 9) + (slot & 63) * 8;
        *(uint4*)&s_w[base] = make_uint4(Hu[0], Hu[1], Hu[2], Hu[3]);
    }
    __syncthreads();                                   // B1: feat + W1 + molS-init

    // ---- GEMM1 + gelu + colsum (pure-bf16 MFMA, 8/wave)
    float w2ra[16];
    {
        floatx4 acc0 = {0,0,0,0}, acc1 = {0,0,0,0};
#pragma unroll
        for (int ks = 0; ks < 4; ++ks) {
            const int k0 = (ks << 5) + (g4 << 3);
            const bfrag8 ahi = *(const bfrag8*)&s_fhi[arow][k0];
#pragma unroll
            for (int nt = 0; nt < 2; ++nt) {
                const int base = ((((ks << 3) + (wn << 1) + nt) << 6) + lane) << 3;
                const bfrag8 bhi = *(const bfrag8*)&s_w[base];
                if (nt) acc1 = __builtin_amdgcn_mfma_f32_16x16x32_bf16(ahi, bhi, acc1, 0, 0, 0);
                else    acc0 = __builtin_amdgcn_mfma_f32_16x16x32_bf16(ahi, bhi, acc0, 0, 0, 0);
            }
        }

        // issue W2 pass-1 rows; hidden under gelu/reduce
        {
            const float* src = W2 + (size_t)(kc << 5) * HIDD + gcol;
#pragma unroll
            for (int q = 0; q < 16; ++q) w2ra[q] = src[(size_t)q * HIDD];
        }

#pragma unroll
        for (int nt = 0; nt < 2; ++nt) {
            const float bb = nt ? b1b : b1a;
            const floatx4 a = nt ? acc1 : acc0;
            float s = gelu_fast(a[0] + bb) + gelu_fast(a[1] + bb)
                    + gelu_fast(a[2] + bb) + gelu_fast(a[3] + bb);
            s += __shfl_xor(s, 16, 64);
            s += __shfl_xor(s, 32, 64);
            if (lane < 16) atomicAdd(&s_molS[colbase + (nt << 4)], s);
        }
    }
    __syncthreads();                                   // B2: s_molS complete

    // ---- GEMV: u[gcol] partials over 32 k's (two 16-k passes)
    {
        float w2rb[16];
        const float* src2 = W2 + (size_t)((kc << 5) + 16) * HIDD + gcol;
#pragma unroll
        for (int q = 0; q < 16; ++q) w2rb[q] = src2[(size_t)q * HIDD];

        float acc = 0.0f;
        float4 m4[4];
#pragma unroll
        for (int p = 0; p < 4; ++p) m4[p] = *(const float4*)&s_molS[(kc << 5) + (p << 2)];
        const float* ms = (const float*)m4;
#pragma unroll
        for (int q = 0; q < 16; ++q) acc = fmaf(ms[q], w2ra[q], acc);
        float4 m4b[4];
#pragma unroll
        for (int p = 0; p < 4; ++p) m4b[p] = *(const float4*)&s_molS[(kc << 5) + 16 + (p << 2)];
        const float* ms2 = (const float*)m4b;
#pragma unroll
        for (int q = 0; q < 16; ++q) acc = fmaf(ms2[q], w2rb[q], acc);

        s_dist[(kc << 7) + gcol] = acc;
    }
    __syncthreads();                                   // B3: partials ready

    // ---- u_h -> ws, then release-fence + flag exchange
    if (tid < HIDD) {
        const float u = ((s_dist[tid] + s_dist[128 + tid])
                       + (s_dist[256 + tid] + s_dist[384 + tid])) * (1.0f / 64.0f);
        ws[(size_t)mol * 256 + (h << 7) + tid] = u;
        __threadfence();                               // release my u stores
    }
    __syncthreads();
    if (tid == 0) {
        atomicExch(&flags[mol * 2 + h], (int)MAGIC);   // announce arrival
        const int other = atomicAdd(&flags[mol * 2 + (1 - h)], 0);
        s_go = (other == (int)MAGIC);                  // other already arrived?
    }
    __syncthreads();
    if (!s_go) return;                                 // first arriver exits

    // ---- last arriver: tail  out[mol] = (u0 + u1 + b2) @ Wo + bo
    __threadfence();                                   // acquire other's u stores
    if (tid < HIDD)
        s_molv[tid] = (ws[(size_t)mol * 256 + tid] + ws[(size_t)mol * 256 + 128 + tid])
                      + b2[tid];
    if (tid == 0) {                                    // reset flags for next replay
        flags[mol * 2 + 0] = 0;
        flags[mol * 2 + 1] = 0;
    }
    __syncthreads();

    {
        float a0 = 0.f, a1 = 0.f, a2 = 0.f, a3 = 0.f;  // 4-way ILP over k
        const float* wop = Wo + tid;
#pragma unroll 8
        for (int k = 0; k < HIDD; k += 4) {
            a0 = fmaf(s_molv[k + 0], wop[(size_t)(k + 0) << 9], a0);
            a1 = fmaf(s_molv[k + 1], wop[(size_t)(k + 1) << 9], a1);
            a2 = fmaf(s_molv[k + 2], wop[(size_t)(k + 2) << 9], a2);
            a3 = fmaf(s_molv[k + 3], wop[(size_t)(k + 3) << 9], a3);
        }
        out[(size_t)mol * OUTD + tid] = ((a0 + a1) + (a2 + a3)) + bo[tid];
    }
}
} // namespace

extern "C" void kernel_launch(void* const* d_in, const int* in_sizes, int n_in,
                              void* d_out, int out_size, void* d_ws, size_t ws_size,
                              hipStream_t stream) {
    const int*   atomic_nums = (const int*)  d_in[0];
    const float* coords      = (const float*)d_in[1];
    const float* embed_table = (const float*)d_in[2];
    const float* W1          = (const float*)d_in[3];
    const float* b1          = (const float*)d_in[4];
    const float* W2          = (const float*)d_in[5];
    const float* b2          = (const float*)d_in[6];
    const float* Wo          = (const float*)d_in[7];
    const float* bo          = (const float*)d_in[8];
    const float* centers     = (const float*)d_in[9];
    float*       out         = (float*)d_out;
    float*       wsf         = (float*)d_ws;   // needs 258 KB

    mlip_fused2<<<2 * NB, 512, 0, stream>>>(atomic_nums, coords, embed_table,
                                            W1, b1, W2, b2, Wo, bo, centers,
                                            wsf, out);
}

// Round 19
// 19.831 us; speedup vs baseline: 4.9313x; 4.9313x over previous
//
#include <hip/hip_runtime.h>
#include <math.h>

namespace {
constexpr int NB   = 256;
constexpr int NA   = 64;
constexpr int EMBD = 64;
constexpr int HIDD = 128;
constexpr int OUTD = 512;
constexpr int FPS  = 136;  // short-stride for bf16 LDS tiles
constexpr int DSTR = 68;   // padded float-stride for s_dist

typedef __attribute__((ext_vector_type(8))) short bfrag8;
typedef __attribute__((ext_vector_type(4))) float floatx4;

__device__ __forceinline__ unsigned short bf16_rne(float f) {
    unsigned u = __float_as_uint(f);
    u += 0x7fffu + ((u >> 16) & 1u);
    return (unsigned short)(u >> 16);
}

// branch-free exact-GELU: erf via Abramowitz-Stegun 7.1.26 (|err| <= 1.5e-7)
__device__ __forceinline__ float gelu_fast(float x) {
    const float ax = fabsf(x) * 0.7071067811865475f;
    const float t  = __builtin_amdgcn_rcpf(fmaf(0.3275911f, ax, 1.0f));
    float p = fmaf(1.061405429f, t, -1.453152027f);
    p = fmaf(p, t, 1.421413741f);
    p = fmaf(p, t, -0.284496736f);
    p = fmaf(p, t, 0.254829592f);
    p = p * t;
    const float e = __builtin_amdgcn_exp2f(-1.4426950408889634f * ax * ax);
    const float erfx = copysignf(fmaf(-p, e, 1.0f), x);
    const float hx   = 0.5f * x;
    return fmaf(hx, erfx, hx);
}

// ---- kernel1: half-molecule front (R17-proven). block (mol=bid>>1, h=bid&1),
// 512 threads, ~51 KB LDS => 2 blocks/CU co-resident (independent barrier domains).
__global__ __launch_bounds__(512, 4)
void mlip_front(const int*   __restrict__ atomic_nums,
                const float* __restrict__ coords,
                const float* __restrict__ embed_table,
                const float* __restrict__ W1, const float* __restrict__ b1,
                const float* __restrict__ W2,
                const float* __restrict__ centers,
                float*       __restrict__ ws)
{
    const int bid  = blockIdx.x;
    const int mol  = bid >> 1, h = bid & 1;
    const int tid  = threadIdx.x;
    const int lane = tid & 63;
    const int wid  = tid >> 6;            // 8 waves

    __shared__ float s_dist[32 * DSTR];   // 8.5 KB; reused as GEMV partial buf
    __shared__ short s_w[16384];          // 32 KB: W1 frags (hi only)
    __shared__ short s_fhi[32][FPS];      // 8.5 KB feat (this half's 32 rows)
    __shared__ float s_molS[HIDD];        // atomic col-sums of gelu out

    // ---- tiling ids (8 waves = 2 wm x 4 wn; wave = 16 rows x 32 cols)
    const int wn      = wid >> 1;
    const int lrow    = lane & 15, g4 = lane >> 4;
    const int arow    = ((wid & 1) << 4) + lrow;      // local row [0,32)
    const int colbase = (wn << 5) + lrow;

    // ---- GEMV ids: col x 4-way k-split (32 k's per thread, two 16-k passes)
    const int gcol = tid & 127, kc = tid >> 7;        // kc in [0,4)

    // ---- gauss ids: thread = (local row, g-chunk, j-quarter)
    const int grow = tid >> 4;            // [0,32)
    const int gch  = (tid >> 2) & 3;
    const int jq   = tid & 3;

    const float b1a = b1[colbase];
    const float b1b = b1[colbase + 16];
    const float c0  = centers[gch << 4];

    if (tid < HIDD) s_molS[tid] = 0.0f;

    // ---- W1 loads phase A (slots 0..1023)
    float w1v[16];
#pragma unroll
    for (int a = 0; a < 2; ++a) {
        const int slot = (a << 9) + tid;
        const int fg = slot >> 6, ls = slot & 63;
        const int k0 = ((fg >> 3) << 5) + ((ls >> 4) << 3);
        const int n  = ((fg & 7) << 4) + (ls & 15);
        const float* src = W1 + (size_t)k0 * HIDD + n;
#pragma unroll
        for (int r = 0; r < 8; ++r) w1v[a * 8 + r] = src[(size_t)r * HIDD];
    }

    // ---- per-lane coords (atom = lane, all 64 atoms of the molecule)
    const float* cbase = coords + (size_t)mol * NA * 3;
    const float cx = cbase[lane * 3 + 0];
    const float cy = cbase[lane * 3 + 1];
    const float cz = cbase[lane * 3 + 2];

    // ---- embedding for this half's 32 rows
    {
        const int i = tid >> 4, e4 = (tid & 15) << 2;
        const int z = atomic_nums[mol * NA + (h << 5) + i];
        const float4 ev = *(const float4*)(embed_table + (size_t)z * EMBD + e4);
        short4 h4;
        const float v[4] = {ev.x, ev.y, ev.z, ev.w};
        short* hp = (short*)&h4;
#pragma unroll
        for (int q = 0; q < 4; ++q) hp[q] = (short)bf16_rne(v[q]);
        *(short4*)&s_fhi[i][e4] = h4;
    }

    // ---- dists: wave w writes local rows 4w..4w+3 — exactly the rows its own
    // gauss threads (grow = tid>>4) read  =>  within-wave dep, no barrier
#pragma unroll
    for (int it = 0; it < 4; ++it) {
        const int i  = (wid << 2) + it;               // local row
        const int gi = (h << 5) + i;                  // global atom index
        const float xi = __shfl(cx, gi, 64);
        const float yi = __shfl(cy, gi, 64);
        const float zi = __shfl(cz, gi, 64);
        const float dx = xi - cx, dy = yi - cy, dz = zi - cz;
        const float sq = dx * dx + dy * dy + dz * dz;
        s_dist[i * DSTR + lane] = sq > 0.0f ? sqrtf(sq) : 0.0f;
    }

    // ---- convert W1 phase A -> s_w
#pragma unroll
    for (int a = 0; a < 2; ++a) {
        unsigned Hu[4];
#pragma unroll
        for (int p = 0; p < 4; ++p) {
            const float x = w1v[a * 8 + 2 * p], y = w1v[a * 8 + 2 * p + 1];
            unsigned hh;
            asm("v_cvt_pk_bf16_f32 %0, %1, %2" : "=v"(hh) : "v"(x), "v"(y));
            Hu[p] = hh;
        }
        const int slot = (a << 9) + tid;
        const int base = ((slot >> 6) << 9) + (slot & 63) * 8;
        *(uint4*)&s_w[base] = make_uint4(Hu[0], Hu[1], Hu[2], Hu[3]);
    }

    // ---- issue W1 phase B loads (slots 1024..2047); they land during gauss
#pragma unroll
    for (int a = 0; a < 2; ++a) {
        const int slot = ((a + 2) << 9) + tid;
        const int fg = slot >> 6, ls = slot & 63;
        const int k0 = ((fg >> 3) << 5) + ((ls >> 4) << 3);
        const int n  = ((fg & 7) << 4) + (ls & 15);
        const float* src = W1 + (size_t)k0 * HIDD + n;
#pragma unroll
        for (int r = 0; r < 8; ++r) w1v[a * 8 + r] = src[(size_t)r * HIDD];
    }

    // ---- gaussian smear (2 ops/term, 4-way ILP chains)
    {
        constexpr float L2E   = 1.4426950408889634f;
        constexpr float DELTA = 10.0f / 63.0f;
        constexpr float K2L   = -2.0f * L2E;
        constexpr float UA    = 4.0f * DELTA * L2E;
        const float P1  = 0.95085835f,  P2  = 0.81745274f, P3  = 0.63539088f,
                    P4  = 0.44653019f,  P5  = 0.28372112f, P6  = 0.16299117f,
                    P7  = 0.08465801f,  P8  = 0.03975530f, P9  = 0.01688004f,
                    P10 = 0.00647989f,  P11 = 0.00224901f, P12 = 0.00070576f,
                    P13 = 0.00020024f,  P14 = 5.136543e-5f, P15 = 1.191313e-5f;

        float acc[16];
#pragma unroll
        for (int q = 0; q < 16; ++q) acc[q] = 0.0f;

        const float* drow = &s_dist[grow * DSTR + (jq << 4)];
#pragma unroll
        for (int j4 = 0; j4 < 4; ++j4) {
            const float4 d4 = *(const float4*)(drow + (j4 << 2));
            const float dv[4] = {d4.x, d4.y, d4.z, d4.w};
#pragma unroll
            for (int jj = 0; jj < 4; ++jj) {
                const float x  = dv[jj] - c0;
                const float A  = __builtin_amdgcn_exp2f(K2L * x * x);
                const float r  = __builtin_amdgcn_exp2f(UA * x);
                const float r2 = r * r, r4 = r2 * r2;
                float s0 = A, s1 = A * r, s2 = A * r2, s3 = s1 * r2;
                acc[0] += s0;
                acc[1]  = fmaf(s1, P1,  acc[1]);
                acc[2]  = fmaf(s2, P2,  acc[2]);
                acc[3]  = fmaf(s3, P3,  acc[3]);
                s0 *= r4; s1 *= r4; s2 *= r4; s3 *= r4;
                acc[4]  = fmaf(s0, P4,  acc[4]);
                acc[5]  = fmaf(s1, P5,  acc[5]);
                acc[6]  = fmaf(s2, P6,  acc[6]);
                acc[7]  = fmaf(s3, P7,  acc[7]);
                s0 *= r4; s1 *= r4; s2 *= r4; s3 *= r4;
                acc[8]  = fmaf(s0, P8,  acc[8]);
                acc[9]  = fmaf(s1, P9,  acc[9]);
                acc[10] = fmaf(s2, P10, acc[10]);
                acc[11] = fmaf(s3, P11, acc[11]);
                s0 *= r4; s1 *= r4; s2 *= r4; s3 *= r4;
                acc[12] = fmaf(s0, P12, acc[12]);
                acc[13] = fmaf(s1, P13, acc[13]);
                acc[14] = fmaf(s2, P14, acc[14]);
                acc[15] = fmaf(s3, P15, acc[15]);
            }
        }
#pragma unroll
        for (int q = 0; q < 16; ++q) {
            acc[q] += __shfl_xor(acc[q], 1, 64);
            acc[q] += __shfl_xor(acc[q], 2, 64);
        }
        if (jq == 0) {
            unsigned* hp = (unsigned*)&s_fhi[grow][EMBD + (gch << 4)];
#pragma unroll
            for (int q2 = 0; q2 < 8; ++q2) {
                const unsigned h0 = bf16_rne(acc[2 * q2]     * (1.0f / 64.0f));
                const unsigned h1 = bf16_rne(acc[2 * q2 + 1] * (1.0f / 64.0f));
                hp[q2] = h0 | (h1 << 16);
            }
        }
    }

    // ---- convert W1 phase B -> s_w
#pragma unroll
    for (int a = 0; a < 2; ++a) {
        unsigned Hu[4];
#pragma unroll
        for (int p = 0; p < 4; ++p) {
            const float x = w1v[a * 8 + 2 * p], y = w1v[a * 8 + 2 * p + 1];
            unsigned hh;
            asm("v_cvt_pk_bf16_f32 %0, %1, %2" : "=v"(hh) : "v"(x), "v"(y));
            Hu[p] = hh;
        }
        const int slot = ((a + 2) << 9) + tid;
        const int base = ((slot >> 6) << 9) + (slot & 63) * 8;
        *(uint4*)&s_w[base] = make_uint4(Hu[0], Hu[1], Hu[2], Hu[3]);
    }
    __syncthreads();                                   // B1: feat + W1 + molS-init

    // ---- GEMM1 + gelu + colsum (pure-bf16 MFMA, 8/wave)
    float w2ra[16];
    {
        floatx4 acc0 = {0,0,0,0}, acc1 = {0,0,0,0};
#pragma unroll
        for (int ks = 0; ks < 4; ++ks) {
            const int k0 = (ks << 5) + (g4 << 3);
            const bfrag8 ahi = *(const bfrag8*)&s_fhi[arow][k0];
#pragma unroll
            for (int nt = 0; nt < 2; ++nt) {
                const int base = ((((ks << 3) + (wn << 1) + nt) << 6) + lane) << 3;
                const bfrag8 bhi = *(const bfrag8*)&s_w[base];
                if (nt) acc1 = __builtin_amdgcn_mfma_f32_16x16x32_bf16(ahi, bhi, acc1, 0, 0, 0);
                else    acc0 = __builtin_amdgcn_mfma_f32_16x16x32_bf16(ahi, bhi, acc0, 0, 0, 0);
            }
        }

        // issue W2 pass-1 rows (k in [kc*32, kc*32+16)); hidden under gelu/reduce
        {
            const float* src = W2 + (size_t)(kc << 5) * HIDD + gcol;
#pragma unroll
            for (int q = 0; q < 16; ++q) w2ra[q] = src[(size_t)q * HIDD];
        }

#pragma unroll
        for (int nt = 0; nt < 2; ++nt) {
            const float bb = nt ? b1b : b1a;
            const floatx4 a = nt ? acc1 : acc0;
            float s = gelu_fast(a[0] + bb) + gelu_fast(a[1] + bb)
                    + gelu_fast(a[2] + bb) + gelu_fast(a[3] + bb);
            s += __shfl_xor(s, 16, 64);
            s += __shfl_xor(s, 32, 64);
            if (lane < 16) atomicAdd(&s_molS[colbase + (nt << 4)], s);
        }
    }
    __syncthreads();                                   // B2: s_molS complete

    // ---- GEMV: u[gcol] partials over 32 k's (two 16-k passes)
    {
        float w2rb[16];
        const float* src2 = W2 + (size_t)((kc << 5) + 16) * HIDD + gcol;
#pragma unroll
        for (int q = 0; q < 16; ++q) w2rb[q] = src2[(size_t)q * HIDD];

        float acc = 0.0f;
        float4 m4[4];
#pragma unroll
        for (int p = 0; p < 4; ++p) m4[p] = *(const float4*)&s_molS[(kc << 5) + (p << 2)];
        const float* ms = (const float*)m4;
#pragma unroll
        for (int q = 0; q < 16; ++q) acc = fmaf(ms[q], w2ra[q], acc);
        float4 m4b[4];
#pragma unroll
        for (int p = 0; p < 4; ++p) m4b[p] = *(const float4*)&s_molS[(kc << 5) + 16 + (p << 2)];
        const float* ms2 = (const float*)m4b;
#pragma unroll
        for (int q = 0; q < 16; ++q) acc = fmaf(ms2[q], w2rb[q], acc);

        s_dist[(kc << 7) + gcol] = acc;                // partials (s_dist is dead)
    }
    __syncthreads();                                   // B3: partials ready

    if (tid < HIDD) {
        const float u = ((s_dist[tid] + s_dist[128 + tid])
                       + (s_dist[256 + tid] + s_dist[384 + tid])) * (1.0f / 64.0f);
        ws[(size_t)mol * 256 + (h << 7) + tid] = u;    // plain store: no init needed
    }
}

// ---- kernel2: 2 molecules per block (128 blocks x 512 threads).
// Each Wo element loaded once feeds 2 FMAs -> Wo L2 traffic halved vs 1 mol/block.
__global__ __launch_bounds__(512, 2)
void mlip_tail(const float* __restrict__ b2,
               const float* __restrict__ Wo, const float* __restrict__ bo,
               const float* __restrict__ ws, float* __restrict__ out)
{
    const int mp  = blockIdx.x;          // mols 2mp, 2mp+1
    const int tid = threadIdx.x;         // col = tid
    __shared__ float s_molv[2][HIDD];

    if (tid < 256) {
        const int m = tid >> 7, c = tid & 127;
        const size_t base = (size_t)(2 * mp + m) * 256;
        s_molv[m][c] = (ws[base + c] + ws[base + 128 + c]) + b2[c];
    }
    __syncthreads();

    float a0 = bo[tid], a1 = a0;
    const float* wop = Wo + tid;
#pragma unroll 8
    for (int k = 0; k < HIDD; ++k) {
        const float w = wop[(size_t)k << 9];           // Wo[k][tid], coalesced
        a0 = fmaf(s_molv[0][k], w, a0);
        a1 = fmaf(s_molv[1][k], w, a1);
    }
    out[(size_t)(2 * mp)     * OUTD + tid] = a0;
    out[(size_t)(2 * mp + 1) * OUTD + tid] = a1;
}
} // namespace

extern "C" void kernel_launch(void* const* d_in, const int* in_sizes, int n_in,
                              void* d_out, int out_size, void* d_ws, size_t ws_size,
                              hipStream_t stream) {
    const int*   atomic_nums = (const int*)  d_in[0];
    const float* coords      = (const float*)d_in[1];
    const float* embed_table = (const float*)d_in[2];
    const float* W1          = (const float*)d_in[3];
    const float* b1          = (const float*)d_in[4];
    const float* W2          = (const float*)d_in[5];
    const float* b2          = (const float*)d_in[6];
    const float* Wo          = (const float*)d_in[7];
    const float* bo          = (const float*)d_in[8];
    const float* centers     = (const float*)d_in[9];
    float*       out         = (float*)d_out;
    float*       wsf         = (float*)d_ws;   // needs 256 KB

    mlip_front<<<2 * NB, 512, 0, stream>>>(atomic_nums, coords, embed_table,
                                           W1, b1, W2, centers, wsf);
    mlip_tail<<<NB / 2, 512, 0, stream>>>(b2, Wo, bo, wsf, out);
}

// Round 20
// 19.219 us; speedup vs baseline: 5.0883x; 1.0318x over previous
//
#include <hip/hip_runtime.h>
#include <math.h>

namespace {
constexpr int NB   = 256;
constexpr int NA   = 64;
constexpr int EMBD = 64;
constexpr int HIDD = 128;
constexpr int OUTD = 512;
constexpr int FPS  = 136;  // short-stride for bf16 LDS tiles
constexpr int DSTR = 68;   // padded float-stride for s_dist

typedef __attribute__((ext_vector_type(8))) short bfrag8;
typedef __attribute__((ext_vector_type(4))) float floatx4;

__device__ __forceinline__ unsigned short bf16_rne(float f) {
    unsigned u = __float_as_uint(f);
    u += 0x7fffu + ((u >> 16) & 1u);
    return (unsigned short)(u >> 16);
}

// branch-free exact-GELU: erf via Abramowitz-Stegun 7.1.26 (|err| <= 1.5e-7)
__device__ __forceinline__ float gelu_fast(float x) {
    const float ax = fabsf(x) * 0.7071067811865475f;
    const float t  = __builtin_amdgcn_rcpf(fmaf(0.3275911f, ax, 1.0f));
    float p = fmaf(1.061405429f, t, -1.453152027f);
    p = fmaf(p, t, 1.421413741f);
    p = fmaf(p, t, -0.284496736f);
    p = fmaf(p, t, 0.254829592f);
    p = p * t;
    const float e = __builtin_amdgcn_exp2f(-1.4426950408889634f * ax * ax);
    const float erfx = copysignf(fmaf(-p, e, 1.0f), x);
    const float hx   = 0.5f * x;
    return fmaf(hx, erfx, hx);
}

// ---- kernel1: half-molecule front (R17-proven, unchanged). block (mol=bid>>1,
// h=bid&1), 512 threads, ~51 KB LDS => 2 blocks/CU (independent barrier domains).
__global__ __launch_bounds__(512, 4)
void mlip_front(const int*   __restrict__ atomic_nums,
                const float* __restrict__ coords,
                const float* __restrict__ embed_table,
                const float* __restrict__ W1, const float* __restrict__ b1,
                const float* __restrict__ W2,
                const float* __restrict__ centers,
                float*       __restrict__ ws)
{
    const int bid  = blockIdx.x;
    const int mol  = bid >> 1, h = bid & 1;
    const int tid  = threadIdx.x;
    const int lane = tid & 63;
    const int wid  = tid >> 6;            // 8 waves

    __shared__ float s_dist[32 * DSTR];   // 8.5 KB; reused as GEMV partial buf
    __shared__ short s_w[16384];          // 32 KB: W1 frags (hi only)
    __shared__ short s_fhi[32][FPS];      // 8.5 KB feat (this half's 32 rows)
    __shared__ float s_molS[HIDD];        // atomic col-sums of gelu out

    // ---- tiling ids (8 waves = 2 wm x 4 wn; wave = 16 rows x 32 cols)
    const int wn      = wid >> 1;
    const int lrow    = lane & 15, g4 = lane >> 4;
    const int arow    = ((wid & 1) << 4) + lrow;      // local row [0,32)
    const int colbase = (wn << 5) + lrow;

    // ---- GEMV ids: col x 4-way k-split (32 k's per thread, two 16-k passes)
    const int gcol = tid & 127, kc = tid >> 7;        // kc in [0,4)

    // ---- gauss ids: thread = (local row, g-chunk, j-quarter)
    const int grow = tid >> 4;            // [0,32)
    const int gch  = (tid >> 2) & 3;
    const int jq   = tid & 3;

    const float b1a = b1[colbase];
    const float b1b = b1[colbase + 16];
    const float c0  = centers[gch << 4];

    if (tid < HIDD) s_molS[tid] = 0.0f;

    // ---- W1 loads phase A (slots 0..1023)
    float w1v[16];
#pragma unroll
    for (int a = 0; a < 2; ++a) {
        const int slot = (a << 9) + tid;
        const int fg = slot >> 6, ls = slot & 63;
        const int k0 = ((fg >> 3) << 5) + ((ls >> 4) << 3);
        const int n  = ((fg & 7) << 4) + (ls & 15);
        const float* src = W1 + (size_t)k0 * HIDD + n;
#pragma unroll
        for (int r = 0; r < 8; ++r) w1v[a * 8 + r] = src[(size_t)r * HIDD];
    }

    // ---- per-lane coords (atom = lane, all 64 atoms of the molecule)
    const float* cbase = coords + (size_t)mol * NA * 3;
    const float cx = cbase[lane * 3 + 0];
    const float cy = cbase[lane * 3 + 1];
    const float cz = cbase[lane * 3 + 2];

    // ---- embedding for this half's 32 rows
    {
        const int i = tid >> 4, e4 = (tid & 15) << 2;
        const int z = atomic_nums[mol * NA + (h << 5) + i];
        const float4 ev = *(const float4*)(embed_table + (size_t)z * EMBD + e4);
        short4 h4;
        const float v[4] = {ev.x, ev.y, ev.z, ev.w};
        short* hp = (short*)&h4;
#pragma unroll
        for (int q = 0; q < 4; ++q) hp[q] = (short)bf16_rne(v[q]);
        *(short4*)&s_fhi[i][e4] = h4;
    }

    // ---- dists: wave w writes local rows 4w..4w+3 — exactly the rows its own
    // gauss threads (grow = tid>>4) read  =>  within-wave dep, no barrier
#pragma unroll
    for (int it = 0; it < 4; ++it) {
        const int i  = (wid << 2) + it;               // local row
        const int gi = (h << 5) + i;                  // global atom index
        const float xi = __shfl(cx, gi, 64);
        const float yi = __shfl(cy, gi, 64);
        const float zi = __shfl(cz, gi, 64);
        const float dx = xi - cx, dy = yi - cy, dz = zi - cz;
        const float sq = dx * dx + dy * dy + dz * dz;
        s_dist[i * DSTR + lane] = sq > 0.0f ? sqrtf(sq) : 0.0f;
    }

    // ---- convert W1 phase A -> s_w
#pragma unroll
    for (int a = 0; a < 2; ++a) {
        unsigned Hu[4];
#pragma unroll
        for (int p = 0; p < 4; ++p) {
            const float x = w1v[a * 8 + 2 * p], y = w1v[a * 8 + 2 * p + 1];
            unsigned hh;
            asm("v_cvt_pk_bf16_f32 %0, %1, %2" : "=v"(hh) : "v"(x), "v"(y));
            Hu[p] = hh;
        }
        const int slot = (a << 9) + tid;
        const int base = ((slot >> 6) << 9) + (slot & 63) * 8;
        *(uint4*)&s_w[base] = make_uint4(Hu[0], Hu[1], Hu[2], Hu[3]);
    }

    // ---- issue W1 phase B loads (slots 1024..2047); they land during gauss
#pragma unroll
    for (int a = 0; a < 2; ++a) {
        const int slot = ((a + 2) << 9) + tid;
        const int fg = slot >> 6, ls = slot & 63;
        const int k0 = ((fg >> 3) << 5) + ((ls >> 4) << 3);
        const int n  = ((fg & 7) << 4) + (ls & 15);
        const float* src = W1 + (size_t)k0 * HIDD + n;
#pragma unroll
        for (int r = 0; r < 8; ++r) w1v[a * 8 + r] = src[(size_t)r * HIDD];
    }

    // ---- gaussian smear (2 ops/term, 4-way ILP chains)
    {
        constexpr float L2E   = 1.4426950408889634f;
        constexpr float DELTA = 10.0f / 63.0f;
        constexpr float K2L   = -2.0f * L2E;
        constexpr float UA    = 4.0f * DELTA * L2E;
        const float P1  = 0.95085835f,  P2  = 0.81745274f, P3  = 0.63539088f,
                    P4  = 0.44653019f,  P5  = 0.28372112f, P6  = 0.16299117f,
                    P7  = 0.08465801f,  P8  = 0.03975530f, P9  = 0.01688004f,
                    P10 = 0.00647989f,  P11 = 0.00224901f, P12 = 0.00070576f,
                    P13 = 0.00020024f,  P14 = 5.136543e-5f, P15 = 1.191313e-5f;

        float acc[16];
#pragma unroll
        for (int q = 0; q < 16; ++q) acc[q] = 0.0f;

        const float* drow = &s_dist[grow * DSTR + (jq << 4)];
#pragma unroll
        for (int j4 = 0; j4 < 4; ++j4) {
            const float4 d4 = *(const float4*)(drow + (j4 << 2));
            const float dv[4] = {d4.x, d4.y, d4.z, d4.w};
#pragma unroll
            for (int jj = 0; jj < 4; ++jj) {
                const float x  = dv[jj] - c0;
                const float A  = __builtin_amdgcn_exp2f(K2L * x * x);
                const float r  = __builtin_amdgcn_exp2f(UA * x);
                const float r2 = r * r, r4 = r2 * r2;
                float s0 = A, s1 = A * r, s2 = A * r2, s3 = s1 * r2;
                acc[0] += s0;
                acc[1]  = fmaf(s1, P1,  acc[1]);
                acc[2]  = fmaf(s2, P2,  acc[2]);
                acc[3]  = fmaf(s3, P3,  acc[3]);
                s0 *= r4; s1 *= r4; s2 *= r4; s3 *= r4;
                acc[4]  = fmaf(s0, P4,  acc[4]);
                acc[5]  = fmaf(s1, P5,  acc[5]);
                acc[6]  = fmaf(s2, P6,  acc[6]);
                acc[7]  = fmaf(s3, P7,  acc[7]);
                s0 *= r4; s1 *= r4; s2 *= r4; s3 *= r4;
                acc[8]  = fmaf(s0, P8,  acc[8]);
                acc[9]  = fmaf(s1, P9,  acc[9]);
                acc[10] = fmaf(s2, P10, acc[10]);
                acc[11] = fmaf(s3, P11, acc[11]);
                s0 *= r4; s1 *= r4; s2 *= r4; s3 *= r4;
                acc[12] = fmaf(s0, P12, acc[12]);
                acc[13] = fmaf(s1, P13, acc[13]);
                acc[14] = fmaf(s2, P14, acc[14]);
                acc[15] = fmaf(s3, P15, acc[15]);
            }
        }
#pragma unroll
        for (int q = 0; q < 16; ++q) {
            acc[q] += __shfl_xor(acc[q], 1, 64);
            acc[q] += __shfl_xor(acc[q], 2, 64);
        }
        if (jq == 0) {
            unsigned* hp = (unsigned*)&s_fhi[grow][EMBD + (gch << 4)];
#pragma unroll
            for (int q2 = 0; q2 < 8; ++q2) {
                const unsigned h0 = bf16_rne(acc[2 * q2]     * (1.0f / 64.0f));
                const unsigned h1 = bf16_rne(acc[2 * q2 + 1] * (1.0f / 64.0f));
                hp[q2] = h0 | (h1 << 16);
            }
        }
    }

    // ---- convert W1 phase B -> s_w
#pragma unroll
    for (int a = 0; a < 2; ++a) {
        unsigned Hu[4];
#pragma unroll
        for (int p = 0; p < 4; ++p) {
            const float x = w1v[a * 8 + 2 * p], y = w1v[a * 8 + 2 * p + 1];
            unsigned hh;
            asm("v_cvt_pk_bf16_f32 %0, %1, %2" : "=v"(hh) : "v"(x), "v"(y));
            Hu[p] = hh;
        }
        const int slot = ((a + 2) << 9) + tid;
        const int base = ((slot >> 6) << 9) + (slot & 63) * 8;
        *(uint4*)&s_w[base] = make_uint4(Hu[0], Hu[1], Hu[2], Hu[3]);
    }
    __syncthreads();                                   // B1: feat + W1 + molS-init

    // ---- GEMM1 + gelu + colsum (pure-bf16 MFMA, 8/wave)
    float w2ra[16];
    {
        floatx4 acc0 = {0,0,0,0}, acc1 = {0,0,0,0};
#pragma unroll
        for (int ks = 0; ks < 4; ++ks) {
            const int k0 = (ks << 5) + (g4 << 3);
            const bfrag8 ahi = *(const bfrag8*)&s_fhi[arow][k0];
#pragma unroll
            for (int nt = 0; nt < 2; ++nt) {
                const int base = ((((ks << 3) + (wn << 1) + nt) << 6) + lane) << 3;
                const bfrag8 bhi = *(const bfrag8*)&s_w[base];
                if (nt) acc1 = __builtin_amdgcn_mfma_f32_16x16x32_bf16(ahi, bhi, acc1, 0, 0, 0);
                else    acc0 = __builtin_amdgcn_mfma_f32_16x16x32_bf16(ahi, bhi, acc0, 0, 0, 0);
            }
        }

        // issue W2 pass-1 rows (k in [kc*32, kc*32+16)); hidden under gelu/reduce
        {
            const float* src = W2 + (size_t)(kc << 5) * HIDD + gcol;
#pragma unroll
            for (int q = 0; q < 16; ++q) w2ra[q] = src[(size_t)q * HIDD];
        }

#pragma unroll
        for (int nt = 0; nt < 2; ++nt) {
            const float bb = nt ? b1b : b1a;
            const floatx4 a = nt ? acc1 : acc0;
            float s = gelu_fast(a[0] + bb) + gelu_fast(a[1] + bb)
                    + gelu_fast(a[2] + bb) + gelu_fast(a[3] + bb);
            s += __shfl_xor(s, 16, 64);
            s += __shfl_xor(s, 32, 64);
            if (lane < 16) atomicAdd(&s_molS[colbase + (nt << 4)], s);
        }
    }
    __syncthreads();                                   // B2: s_molS complete

    // ---- GEMV: u[gcol] partials over 32 k's (two 16-k passes)
    {
        float w2rb[16];
        const float* src2 = W2 + (size_t)((kc << 5) + 16) * HIDD + gcol;
#pragma unroll
        for (int q = 0; q < 16; ++q) w2rb[q] = src2[(size_t)q * HIDD];

        float acc = 0.0f;
        float4 m4[4];
#pragma unroll
        for (int p = 0; p < 4; ++p) m4[p] = *(const float4*)&s_molS[(kc << 5) + (p << 2)];
        const float* ms = (const float*)m4;
#pragma unroll
        for (int q = 0; q < 16; ++q) acc = fmaf(ms[q], w2ra[q], acc);
        float4 m4b[4];
#pragma unroll
        for (int p = 0; p < 4; ++p) m4b[p] = *(const float4*)&s_molS[(kc << 5) + 16 + (p << 2)];
        const float* ms2 = (const float*)m4b;
#pragma unroll
        for (int q = 0; q < 16; ++q) acc = fmaf(ms2[q], w2rb[q], acc);

        s_dist[(kc << 7) + gcol] = acc;                // partials (s_dist is dead)
    }
    __syncthreads();                                   // B3: partials ready

    if (tid < HIDD) {
        const float u = ((s_dist[tid] + s_dist[128 + tid])
                       + (s_dist[256 + tid] + s_dist[384 + tid])) * (1.0f / 64.0f);
        ws[(size_t)mol * 256 + (h << 7) + tid] = u;    // plain store: no init needed
    }
}

// ---- kernel2: 1 molecule per block (256 blocks, R17 grid) with 4-way k-ILP:
// breaks the 128-deep serial FMA chain (~512 cyc) into 4 chains (~128 cyc).
__global__ __launch_bounds__(512, 2)
void mlip_tail(const float* __restrict__ b2,
               const float* __restrict__ Wo, const float* __restrict__ bo,
               const float* __restrict__ ws, float* __restrict__ out)
{
    const int mol = blockIdx.x;
    const int tid = threadIdx.x;
    __shared__ float s_molv[HIDD];

    if (tid < HIDD)
        s_molv[tid] = (ws[(size_t)mol * 256 + tid] + ws[(size_t)mol * 256 + 128 + tid])
                      + b2[tid];
    __syncthreads();

    float a0 = 0.f, a1 = 0.f, a2 = 0.f, a3 = 0.f;
    const float* wop = Wo + tid;
#pragma unroll 8
    for (int k = 0; k < HIDD; k += 4) {
        a0 = fmaf(s_molv[k + 0], wop[(size_t)(k + 0) << 9], a0);
        a1 = fmaf(s_molv[k + 1], wop[(size_t)(k + 1) << 9], a1);
        a2 = fmaf(s_molv[k + 2], wop[(size_t)(k + 2) << 9], a2);
        a3 = fmaf(s_molv[k + 3], wop[(size_t)(k + 3) << 9], a3);
    }
    out[(size_t)mol * OUTD + tid] = ((a0 + a1) + (a2 + a3)) + bo[tid];
}
} // namespace

extern "C" void kernel_launch(void* const* d_in, const int* in_sizes, int n_in,
                              void* d_out, int out_size, void* d_ws, size_t ws_size,
                              hipStream_t stream) {
    const int*   atomic_nums = (const int*)  d_in[0];
    const float* coords      = (const float*)d_in[1];
    const float* embed_table = (const float*)d_in[2];
    const float* W1          = (const float*)d_in[3];
    const float* b1          = (const float*)d_in[4];
    const float* W2          = (const float*)d_in[5];
    const float* b2          = (const float*)d_in[6];
    const float* Wo          = (const float*)d_in[7];
    const float* bo          = (const float*)d_in[8];
    const float* centers     = (const float*)d_in[9];
    float*       out         = (float*)d_out;
    float*       wsf         = (float*)d_ws;   // needs 256 KB

    mlip_front<<<2 * NB, 512, 0, stream>>>(atomic_nums, coords, embed_table,
                                           W1, b1, W2, centers, wsf);
    mlip_tail<<<NB, 512, 0, stream>>>(b2, Wo, bo, wsf, out);
}